// Round 6
// baseline (139.394 us; speedup 1.0000x reference)
//
#include <hip/hip_runtime.h>

// Problem constants (N=4, D=H=W=96, corner grid G=97)
#define DHW   884736u          // 96^3
#define HWp   9216u            // 96^2
#define VERTS_ELEMS 2738019u   // 97^3 * 3
#define FACES_OFF   2738019u
#define MASK_OFF    34588515u  // VERTS + FACES elems

#define MASK_BLOCKS  3456u     // 4*DHW/4 voxel-groups / 256
#define FACES_BLOCKS 20736u    // 6*DHW quads / 256
#define VERTS_BLOCKS 2674u     // ceil(ceil(VERTS_ELEMS/4)/256)
#define TOTAL_BLOCKS (MASK_BLOCKS + FACES_BLOCKS + VERTS_BLOCKS)

// _TRI corner-id deltas: delta = oz*9409 + oy*97 + ox; per quad q the 6
// triangle-vertex elements are {d0,d1,d2, d1,d2,d3} of _QUAD[q].
__constant__ int c_tri[6][6] = {
    {0,    1,    97,   1,    97,   98},    // q0 (z-)
    {9409, 9410, 9506, 9410, 9506, 9507},  // q1 (z+)
    {9409, 9410, 0,    9410, 0,    1},     // q2 (y-)
    {97,   98,   9506, 98,   9506, 9507},  // q3 (y+)
    {9409, 0,    9506, 0,    9506, 97},    // q4 (x-)
    {1,    9410, 98,   9410, 98,   9507},  // q5 (x+)
};

// Vector types with reduced (dword) alignment — region offsets are odd
// floats; CDNA global multi-dword ops need only dword alignment. Same
// idiom as clang's __m128_u.
typedef float f4v __attribute__((ext_vector_type(4)));
typedef f4v f4u __attribute__((aligned(4)));
typedef float f2v __attribute__((ext_vector_type(2)));
typedef f2v f2u __attribute__((aligned(4)));

__device__ __forceinline__ void st_nt4(float* p, float a, float b, float c, float d) {
    f4v v = {a, b, c, d};
    __builtin_nontemporal_store(v, (f4u*)p);
}
__device__ __forceinline__ void st_nt2(float* p, float a, float b) {
    f2v v = {a, b};
    __builtin_nontemporal_store(v, (f2u*)p);
}

__global__ void __launch_bounds__(256) cubify_k(const float* __restrict__ p,
                                                float* __restrict__ out) {
    const unsigned bid = blockIdx.x, tid = threadIdx.x;

    if (bid < MASK_BLOCKS) {
        // ---- face_mask: one thread = 4 voxels (x%4==0) x ALL 6 directions ----
        unsigned g    = bid * 256u + tid;      // (n, voxg)
        unsigned n    = g / 221184u;           // DHW/4; block-uniform (864 blk/n)
        unsigned voxg = g - n * 221184u;
        unsigned vox  = voxg * 4u;
        unsigned z = vox / HWp;
        unsigned r = vox - z * HWp;
        unsigned y = r / 96u;
        unsigned x = r - y * 96u;              // x%4==0, group never crosses a row

        const float* pb = p + (size_t)n * DHW;
        float4 s = *(const float4*)(pb + vox);           // self, 16B aligned
        bool s0 = s.x > 0.5f, s1 = s.y > 0.5f, s2 = s.z > 0.5f, s3 = s.w > 0.5f;

        unsigned zm = (z == 0u) ? 95u : z - 1u, zp = (z == 95u) ? 0u : z + 1u;
        unsigned ym = (y == 0u) ? 95u : y - 1u, yp = (y == 95u) ? 0u : y + 1u;
        unsigned rowoff = y * 96u + x;
        float4 nzm = *(const float4*)(pb + zm * HWp + rowoff);
        float4 nzp = *(const float4*)(pb + zp * HWp + rowoff);
        float4 nym = *(const float4*)(pb + z * HWp + ym * 96u + x);
        float4 nyp = *(const float4*)(pb + z * HWp + yp * 96u + x);
        float exm = pb[(x == 0u)  ? vox + 95u : vox - 1u];   // x-1 (wrap)
        float exp_ = pb[(x == 92u) ? vox - 92u : vox + 4u];  // x+4 (wrap)

        float* ob = out + (size_t)MASK_OFF + ((size_t)(n * 6u) * DHW + vox) * 2u;
        auto emit = [&](unsigned q, float a, float b, float c, float d) {
            float v0 = (s0 && !(a > 0.5f)) ? 1.0f : 0.0f;
            float v1 = (s1 && !(b > 0.5f)) ? 1.0f : 0.0f;
            float v2 = (s2 && !(c > 0.5f)) ? 1.0f : 0.0f;
            float v3 = (s3 && !(d > 0.5f)) ? 1.0f : 0.0f;
            float* o = ob + (size_t)q * (DHW * 2u);
            st_nt4(o,     v0, v0, v1, v1);
            st_nt4(o + 4, v2, v2, v3, v3);
        };
        emit(0u, nzm.x, nzm.y, nzm.z, nzm.w);   // z-1
        emit(1u, nzp.x, nzp.y, nzp.z, nzp.w);   // z+1
        emit(2u, nym.x, nym.y, nym.z, nym.w);   // y-1
        emit(3u, nyp.x, nyp.y, nyp.z, nyp.w);   // y+1
        emit(4u, exm,  s.x,  s.y,  s.z);        // x-1
        emit(5u, s.y,  s.z,  s.w,  exp_);       // x+1

    } else if (bid < MASK_BLOCKS + FACES_BLOCKS) {
        // ---- faces: one thread = one quad (6 ids) ----
        unsigned quad = (bid - MASK_BLOCKS) * 256u + tid;
        unsigned q   = quad / DHW;             // block-uniform (DHW%256==0)
        unsigned vox = quad - q * DHW;
        unsigned z = vox / HWp;
        unsigned r = vox - z * HWp;
        unsigned y = r / 96u;
        unsigned x = r - y * 96u;
        unsigned base = (z * 97u + y) * 97u + x;
        const int* t = c_tri[q];
        float* o = out + (size_t)FACES_OFF + (size_t)quad * 6u;
        st_nt4(o, (float)(base + t[0]), (float)(base + t[1]),
                  (float)(base + t[2]), (float)(base + t[3]));
        st_nt2(o + 4, (float)(base + t[4]), (float)(base + t[5]));

    } else {
        // ---- verts: one thread = 4 elements ----
        unsigned i4 = ((bid - (MASK_BLOCKS + FACES_BLOCKS)) * 256u + tid) * 4u;
        if (i4 + 3u < VERTS_ELEMS) {
            float vals[4];
#pragma unroll
            for (int j = 0; j < 4; ++j) {
                unsigned idx = i4 + (unsigned)j;
                unsigned v = idx / 3u;
                unsigned c = idx - v * 3u;
                unsigned z = v / 9409u;
                unsigned r = v - z * 9409u;
                unsigned y = r / 97u;
                unsigned x = r - y * 97u;
                unsigned coord = (c == 0u) ? z : ((c == 1u) ? y : x);
                vals[j] = (float)coord - 0.5f;
            }
            st_nt4(out + i4, vals[0], vals[1], vals[2], vals[3]);
        } else if (i4 < VERTS_ELEMS) {
            for (unsigned idx = i4; idx < VERTS_ELEMS; ++idx) {
                unsigned v = idx / 3u;
                unsigned c = idx - v * 3u;
                unsigned z = v / 9409u;
                unsigned r = v - z * 9409u;
                unsigned y = r / 97u;
                unsigned x = r - y * 97u;
                unsigned coord = (c == 0u) ? z : ((c == 1u) ? y : x);
                out[idx] = (float)coord - 0.5f;
            }
        }
    }
}

extern "C" void kernel_launch(void* const* d_in, const int* in_sizes, int n_in,
                              void* d_out, int out_size, void* d_ws, size_t ws_size,
                              hipStream_t stream) {
    const float* probas = (const float*)d_in[0];
    float* out = (float*)d_out;
    cubify_k<<<TOTAL_BLOCKS, 256, 0, stream>>>(probas, out);
}

// Round 7
// 103.283 us; speedup vs baseline: 1.3496x; 1.3496x over previous
//
#include <hip/hip_runtime.h>

// Problem constants (N=4, D=H=W=96, corner grid G=97)
#define DHW 884736u            // 96^3
#define HWp 9216u              // 96^2

#define VERTS_ELEMS 2738019u   // 97^3*3, region [0, 2738019)
#define FACES_OFF   2738019u   // region [2738019, 34588515)
#define MASK_OFF    34588515u  // region [34588515, 77055843)

// Aligned-window decomposition (all bulk stores 16B-aligned):
//   verts: thread g: floats [16g, 16g+16), g < 171126   (tail 3 in specials)
//   faces: thread m: region floats [12m+1, 12m+13), m < 2654207; m==2654207 tail(11)
//   mask:  per slab s=(n,q) (size 2*DHW, starts ==3 mod 4): thread k:
//          slab floats [16k+1, 16k+17) = pair values vox 8k..8k+8; k < 110591
//          slab head(1)+tail(15) in specials.
#define MASK_WPS     110591u
#define MASK_WINDOWS 2654184u  // 24*110591
#define FACES_PAIRS  2654207u
#define VERTS_WINDOWS 171126u

#define MASK_BLOCKS  10368u    // 2654208 threads (24 idle)
#define FACES_BLOCKS 10368u    // 2654208 threads (last = tail)
#define VERTS_BLOCKS 669u      // 171264 threads (138 idle)
#define TOTAL_BLOCKS (MASK_BLOCKS + FACES_BLOCKS + VERTS_BLOCKS + 1u)

// _TRI corner-id deltas: delta = oz*9409 + oy*97 + ox
__constant__ int c_tri[6][6] = {
    {0,    1,    97,   1,    97,   98},    // q0 (z-)
    {9409, 9410, 9506, 9410, 9506, 9507},  // q1 (z+)
    {9409, 9410, 0,    9410, 0,    1},     // q2 (y-)
    {97,   98,   9506, 98,   9506, 9507},  // q3 (y+)
    {9409, 0,    9506, 0,    9506, 97},    // q4 (x-)
    {1,    9410, 98,   9410, 98,   9507},  // q5 (x+)
};

// dword-aligned vector loads (neighbor rows can sit at odd float offsets)
typedef float f4v __attribute__((ext_vector_type(4)));
typedef f4v f4u __attribute__((aligned(4)));

__device__ __forceinline__ void st4(float* p, float a, float b, float c, float d) {
    *(float4*)p = make_float4(a, b, c, d);   // p is 16B-aligned by construction
}

__device__ __forceinline__ unsigned nbvox(unsigned z, unsigned y, unsigned x,
                                          unsigned axis, bool pos) {
    if (axis == 0u) { unsigned zz = pos ? (z == 95u ? 0u : z + 1u) : (z == 0u ? 95u : z - 1u);
                      return zz * HWp + y * 96u + x; }
    if (axis == 1u) { unsigned yy = pos ? (y == 95u ? 0u : y + 1u) : (y == 0u ? 95u : y - 1u);
                      return z * HWp + yy * 96u + x; }
    unsigned xx = pos ? (x == 95u ? 0u : x + 1u) : (x == 0u ? 95u : x - 1u);
    return z * HWp + y * 96u + xx;
}

__device__ __forceinline__ unsigned quad_base(unsigned quad, unsigned* qd_out) {
    unsigned qd  = quad / DHW;
    unsigned vox = quad - qd * DHW;
    unsigned z = vox / HWp;
    unsigned r = vox - z * HWp;
    unsigned y = r / 96u;
    unsigned x = r - y * 96u;
    *qd_out = qd;
    return (z * 97u + y) * 97u + x;
}

__device__ __forceinline__ float vert_val(unsigned idx) {
    unsigned v = idx / 3u;
    unsigned c = idx - v * 3u;
    unsigned z = v / 9409u;
    unsigned r = v - z * 9409u;
    unsigned y = r / 97u;
    unsigned x = r - y * 97u;
    unsigned coord = (c == 0u) ? z : ((c == 1u) ? y : x);
    return (float)coord - 0.5f;
}

__global__ void __launch_bounds__(256) cubify_k(const float* __restrict__ p,
                                                float* __restrict__ out) {
    const unsigned bid = blockIdx.x, tid = threadIdx.x;

    if (bid < MASK_BLOCKS) {
        // ---- face_mask aligned windows: 16 floats = pair values vox 8k..8k+8 ----
        unsigned w = bid * 256u + tid;
        if (w >= MASK_WINDOWS) return;
        unsigned s = w / MASK_WPS;             // slab (n,q), s<24
        unsigned k = w - s * MASK_WPS;
        unsigned n = s / 6u, q = s - n * 6u;
        unsigned vox0 = 8u * k;
        unsigned z0 = vox0 / HWp;
        unsigned r0 = vox0 - z0 * HWp;
        unsigned y0 = r0 / 96u;
        unsigned x0 = r0 - y0 * 96u;           // multiple of 8

        const float* pb = p + (size_t)n * DHW;
        float4 sa = *(const float4*)(pb + vox0);      // vox0 % 4 == 0 -> aligned
        float4 sb = *(const float4*)(pb + vox0 + 4);
        float  sc = pb[vox0 + 8];
        float sv[9] = {sa.x, sa.y, sa.z, sa.w, sb.x, sb.y, sb.z, sb.w, sc};

        // coords of vox0+8 (may cross row / z-plane)
        unsigned x8 = x0 + 8u, y8 = y0, z8 = z0;
        if (x8 > 95u) { x8 -= 96u; y8 += 1u; if (y8 > 95u) { y8 = 0u; z8 += 1u; } }

        unsigned axis = q >> 1;
        bool pos = (q & 1u) != 0u;
        unsigned nb0 = nbvox(z0, y0, x0, axis, pos);
        unsigned nb8 = nbvox(z8, y8, x8, axis, pos);

        bool fast;
        if (axis == 2u) fast = (x0 != 88u) && (pos || x0 != 0u); // no interior x-wrap
        else            fast = (nb8 == nb0 + 8u);                // z/y wraps only at elem 8

        float nv[9];
        if (fast) {
            f4u na = *(const f4u*)(pb + nb0);
            f4u nb_ = *(const f4u*)(pb + nb0 + 4);
            nv[0]=na.x; nv[1]=na.y; nv[2]=na.z; nv[3]=na.w;
            nv[4]=nb_.x; nv[5]=nb_.y; nv[6]=nb_.z; nv[7]=nb_.w;
            nv[8]=pb[nb0 + 8u];
        } else {
#pragma unroll
            for (int i = 0; i < 9; ++i) {
                unsigned xi = x0 + (unsigned)i, yi = y0, zi = z0;
                if (xi > 95u) { xi -= 96u; yi += 1u; if (yi > 95u) { yi = 0u; zi += 1u; } }
                nv[i] = pb[nbvox(zi, yi, xi, axis, pos)];
            }
        }

        float v[9];
#pragma unroll
        for (int i = 0; i < 9; ++i)
            v[i] = (sv[i] > 0.5f && !(nv[i] > 0.5f)) ? 1.0f : 0.0f;

        float* o = out + (size_t)MASK_OFF + (size_t)s * (2u * DHW) + 16u * k + 1u;
        st4(o,      v[0], v[1], v[1], v[2]);
        st4(o + 4,  v[2], v[3], v[3], v[4]);
        st4(o + 8,  v[4], v[5], v[5], v[6]);
        st4(o + 12, v[6], v[7], v[7], v[8]);

    } else if (bid < MASK_BLOCKS + FACES_BLOCKS) {
        // ---- faces aligned windows: 12 floats [12m+1, 12m+13) ----
        unsigned m = (bid - MASK_BLOCKS) * 256u + tid;
        unsigned qdA, qdB, qdC;
        unsigned bA = quad_base(2u * m,      &qdA);
        unsigned bB = quad_base(2u * m + 1u, &qdB);
        float* o = out + (size_t)FACES_OFF + 12u * (size_t)m + 1u;
        float A1 = (float)(bA + (unsigned)c_tri[qdA][1]);
        float A2 = (float)(bA + (unsigned)c_tri[qdA][2]);
        float A3 = (float)(bA + (unsigned)c_tri[qdA][3]);
        float A4 = (float)(bA + (unsigned)c_tri[qdA][4]);
        float A5 = (float)(bA + (unsigned)c_tri[qdA][5]);
        float B0 = (float)(bB + (unsigned)c_tri[qdB][0]);
        float B1 = (float)(bB + (unsigned)c_tri[qdB][1]);
        float B2 = (float)(bB + (unsigned)c_tri[qdB][2]);
        float B3 = (float)(bB + (unsigned)c_tri[qdB][3]);
        float B4 = (float)(bB + (unsigned)c_tri[qdB][4]);
        float B5 = (float)(bB + (unsigned)c_tri[qdB][5]);
        if (m < FACES_PAIRS) {
            unsigned bC = quad_base(2u * m + 2u, &qdC);
            float C0 = (float)(bC + (unsigned)c_tri[qdC][0]);
            st4(o,     A1, A2, A3, A4);
            st4(o + 4, A5, B0, B1, B2);
            st4(o + 8, B3, B4, B5, C0);
        } else {                       // m == FACES_PAIRS: region tail, 11 floats
            st4(o,     A1, A2, A3, A4);
            st4(o + 4, A5, B0, B1, B2);
            o[8] = B3; o[9] = B4; o[10] = B5;
        }

    } else if (bid < MASK_BLOCKS + FACES_BLOCKS + VERTS_BLOCKS) {
        // ---- verts: thread g = floats [16g, 16g+16) (already aligned) ----
        unsigned g = (bid - (MASK_BLOCKS + FACES_BLOCKS)) * 256u + tid;
        if (g >= VERTS_WINDOWS) return;
        float vals[16];
#pragma unroll
        for (int j = 0; j < 16; ++j) vals[j] = vert_val(16u * g + (unsigned)j);
        float* o = out + 16u * (size_t)g;
        st4(o,      vals[0],  vals[1],  vals[2],  vals[3]);
        st4(o + 4,  vals[4],  vals[5],  vals[6],  vals[7]);
        st4(o + 8,  vals[8],  vals[9],  vals[10], vals[11]);
        st4(o + 12, vals[12], vals[13], vals[14], vals[15]);

    } else {
        // ---- specials: slab heads/tails + region seams ----
        if (tid < 24u) {
            // mask slab head: 1 float at slab base (vox 0, first copy)
            unsigned s = tid, n = s / 6u, q = s - n * 6u;
            unsigned axis = q >> 1;  bool pos = (q & 1u) != 0u;
            const float* pb = p + (size_t)n * DHW;
            bool self = pb[0] > 0.5f;
            bool nb = pb[nbvox(0u, 0u, 0u, axis, pos)] > 0.5f;
            out[(size_t)MASK_OFF + (size_t)s * (2u * DHW)] = (self && !nb) ? 1.0f : 0.0f;
        } else if (tid < 48u) {
            // mask slab tail: 15 floats, vox 884728..884735 (z=95,y=95,x=88..95)
            unsigned s = tid - 24u, n = s / 6u, q = s - n * 6u;
            unsigned axis = q >> 1;  bool pos = (q & 1u) != 0u;
            const float* pb = p + (size_t)n * DHW;
            float v[8];
#pragma unroll
            for (int i = 0; i < 8; ++i) {
                unsigned vox = 884728u + (unsigned)i;
                bool self = pb[vox] > 0.5f;
                bool nb = pb[nbvox(95u, 95u, 88u + (unsigned)i, axis, pos)] > 0.5f;
                v[i] = (self && !nb) ? 1.0f : 0.0f;
            }
            float* o = out + (size_t)MASK_OFF + (size_t)s * (2u * DHW) + 1769457u;
            st4(o,     v[0], v[1], v[1], v[2]);
            st4(o + 4, v[2], v[3], v[3], v[4]);
            st4(o + 8, v[4], v[5], v[5], v[6]);
            o[12] = v[6]; o[13] = v[7]; o[14] = v[7];
        } else if (tid == 48u) {
            // verts tail (3) + faces head (cid of quad0,e0 = 0 -> 0.0f)
            st4(out + 2738016u, 95.5f, 95.5f, 95.5f, 0.0f);
        }
    }
}

extern "C" void kernel_launch(void* const* d_in, const int* in_sizes, int n_in,
                              void* d_out, int out_size, void* d_ws, size_t ws_size,
                              hipStream_t stream) {
    const float* probas = (const float*)d_in[0];
    float* out = (float*)d_out;
    cubify_k<<<TOTAL_BLOCKS, 256, 0, stream>>>(probas, out);
}

// Round 8
// 62.510 us; speedup vs baseline: 2.2299x; 1.6523x over previous
//
#include <hip/hip_runtime.h>

// Problem constants (N=4, D=H=W=96, corner grid 97)
#define DHW  884736u           // 96^3
#define HWp  9216u             // 96^2
#define SLAB 1769472u          // 2*DHW (one (n,q) mask slab, floats)

#define FACES_OFF 2738019u     // faces region [2738019, 34588515)
#define MASK_OFF  34588515u    // mask  region [34588515, 77055843)

// Window index t covers absolute floats [4t, 4t+4), all 16B-aligned,
// consecutive t -> consecutive lanes -> full-line wave stores.
#define VERTS_END_T  684504u   // verts windows: t < 684504 (covers [0, 2738016))
// t == 684504: seam1 {verts tail 3, faces f=0}
#define FACES_SEAM_T 8647128u  // faces windows: 684505 <= t < 8647128
// t == 8647128: seam2 {faces tail 3, mask f=0}
#define MASK_END_T   19263960u // mask windows: 8647129 <= t < 19263960
// t == 19263960: mask tail 3 floats (scalar)
#define TOTAL_BLOCKS 75250u    // 19264000 threads

// corner-delta table: cdelta[q][c] = dot(_QUAD[q][c], (9409, 97, 1));
// triangle elem e -> corner c = e<3 ? e : e-2.
__constant__ unsigned cdelta[6][4] = {
    {0u,    1u,    97u,   98u},    // q0 (z-)
    {9409u, 9410u, 9506u, 9507u},  // q1 (z+)
    {9409u, 9410u, 0u,    1u},     // q2 (y-)
    {97u,   98u,   9506u, 9507u},  // q3 (y+)
    {9409u, 0u,    9506u, 97u},    // q4 (x-)
    {1u,    9410u, 98u,   9507u},  // q5 (x+)
};

__device__ __forceinline__ void st4(float* p, float a, float b, float c, float d) {
    *(float4*)p = make_float4(a, b, c, d);   // 16B-aligned by construction
}

__device__ __forceinline__ unsigned nbvox(unsigned z, unsigned y, unsigned x,
                                          unsigned axis, bool pos) {
    if (axis == 0u) { unsigned zz = pos ? (z == 95u ? 0u : z + 1u) : (z == 0u ? 95u : z - 1u);
                      return zz * HWp + y * 96u + x; }
    if (axis == 1u) { unsigned yy = pos ? (y == 95u ? 0u : y + 1u) : (y == 0u ? 95u : y - 1u);
                      return z * HWp + yy * 96u + x; }
    unsigned xx = pos ? (x == 95u ? 0u : x + 1u) : (x == 0u ? 95u : x - 1u);
    return z * HWp + y * 96u + xx;
}

__device__ __forceinline__ unsigned quad_base(unsigned Q, unsigned* qd_out) {
    unsigned qd  = Q / DHW;
    unsigned vox = Q - qd * DHW;
    unsigned z = vox / HWp;
    unsigned r = vox - z * HWp;
    unsigned y = r / 96u;
    unsigned x = r - y * 96u;
    *qd_out = qd;
    return (z * 97u + y) * 97u + x;
}

__device__ __forceinline__ float vert_val(unsigned idx) {
    unsigned v = idx / 3u;
    unsigned c = idx - v * 3u;
    unsigned z = v / 9409u;
    unsigned r = v - z * 9409u;
    unsigned y = r / 97u;
    unsigned x = r - y * 97u;
    unsigned coord = (c == 0u) ? z : ((c == 1u) ? y : x);
    return (float)coord - 0.5f;
}

__device__ __forceinline__ float maskval(const float* p, unsigned s, unsigned vox) {
    unsigned n = s / 6u, q = s - n * 6u;
    unsigned z = vox / HWp, r = vox - z * HWp, y = r / 96u, x = r - y * 96u;
    const float* pb = p + (size_t)n * DHW;
    bool self = pb[vox] > 0.5f;
    bool nb = pb[nbvox(z, y, x, q >> 1u, (q & 1u) != 0u)] > 0.5f;
    return (self && !nb) ? 1.0f : 0.0f;
}

__global__ void __launch_bounds__(256) cubify_k(const float* __restrict__ p,
                                                float* __restrict__ out) {
    unsigned t = blockIdx.x * 256u + threadIdx.x;

    if (t < VERTS_END_T) {
        // ---- verts: 4 elements [4t, 4t+4) ----
        unsigned i = 4u * t;
        st4(out + (size_t)i, vert_val(i), vert_val(i + 1u),
                             vert_val(i + 2u), vert_val(i + 3u));

    } else if (t < FACES_SEAM_T) {
        if (t == VERTS_END_T) {
            // verts tail: vert 912672 = (96,96,96) -> 95.5x3; faces f=0 -> cid 0
            st4(out + 2738016u, 95.5f, 95.5f, 95.5f, 0.0f);
            return;
        }
        // ---- faces: region floats [f0, f0+4), f0 = 4t - FACES_OFF (odd) ----
        unsigned f0 = 4u * t - FACES_OFF;
        unsigned q0 = f0 / 6u, e0 = f0 - 6u * q0;   // e0 in {1,3,5}
        unsigned qd0, qd1;
        unsigned b0 = quad_base(q0, &qd0);
        unsigned b1 = quad_base(q0 + 1u, &qd1);     // q0+1 <= 5308415, valid
        float vals[4];
#pragma unroll
        for (int j = 0; j < 4; ++j) {
            unsigned e = e0 + (unsigned)j, b = b0, qd = qd0;
            if (e >= 6u) { e -= 6u; b = b1; qd = qd1; }
            unsigned c = (e < 3u) ? e : e - 2u;
            vals[j] = (float)(b + cdelta[qd][c]);
        }
        st4(out + 4u * (size_t)t, vals[0], vals[1], vals[2], vals[3]);

    } else if (t < MASK_END_T) {
        if (t == FACES_SEAM_T) {
            // faces tail: quad 5308415 (qd=5, vox (95,95,95), base 903165),
            // elems 3,4,5 -> +9410,+98,+9507; mask slab0 f=0: (n0,q0=z-) vox0
            bool self = p[0] > 0.5f, nb = p[875520u] > 0.5f;   // z=95 plane
            st4(out + 34588512u, 912575.0f, 903263.0f, 912672.0f,
                (self && !nb) ? 1.0f : 0.0f);
            return;
        }
        // ---- mask: region floats [f0, f0+4), f0 = 4t - MASK_OFF (odd) ----
        unsigned f0 = 4u * t - MASK_OFF;
        unsigned s  = f0 / SLAB;
        unsigned ff = f0 - s * SLAB;                // odd
        if (ff == 1769469u) {
            // slab-crossing window: vox 884734(c1), 884735(c0,c1), next-slab vox0(c0)
            float v0 = maskval(p, s, 884734u);
            float v1 = maskval(p, s, 884735u);
            float v2 = maskval(p, s + 1u, 0u);
            st4(out + 4u * (size_t)t, v0, v1, v1, v2);
        } else {
            unsigned a = ff >> 1u;                  // window = {v(a), v(a+1), v(a+1), v(a+2)}
            unsigned n = s / 6u, q = s - n * 6u;    // q wave-uniform in practice
            unsigned axis = q >> 1u; bool pos = (q & 1u) != 0u;
            const float* pb = p + (size_t)n * DHW;
            unsigned z0 = a / HWp, r0 = a - z0 * HWp, y0 = r0 / 96u, x0 = r0 - y0 * 96u;
            unsigned x1 = x0 + 1u, y1 = y0, z1 = z0;
            if (x1 > 95u) { x1 = 0u; if (++y1 > 95u) { y1 = 0u; ++z1; } }
            unsigned x2 = x1 + 1u, y2 = y1, z2 = z1;
            if (x2 > 95u) { x2 = 0u; if (++y2 > 95u) { y2 = 0u; ++z2; } }
            float s0 = pb[a], s1 = pb[a + 1u], s2 = pb[a + 2u];
            float m0 = pb[nbvox(z0, y0, x0, axis, pos)];
            float m1 = pb[nbvox(z1, y1, x1, axis, pos)];
            float m2 = pb[nbvox(z2, y2, x2, axis, pos)];
            float v0 = (s0 > 0.5f && !(m0 > 0.5f)) ? 1.0f : 0.0f;
            float v1 = (s1 > 0.5f && !(m1 > 0.5f)) ? 1.0f : 0.0f;
            float v2 = (s2 > 0.5f && !(m2 > 0.5f)) ? 1.0f : 0.0f;
            st4(out + 4u * (size_t)t, v0, v1, v1, v2);
        }

    } else if (t == MASK_END_T) {
        // mask tail: slab 23 (n=3, q=5: x+), vox 884734(c1), 884735(c0,c1)
        const float* pb = p + (size_t)3u * DHW;
        float v34 = (pb[884734u] > 0.5f && !(pb[884735u] > 0.5f)) ? 1.0f : 0.0f;
        float v35 = (pb[884735u] > 0.5f && !(pb[884640u] > 0.5f)) ? 1.0f : 0.0f; // x wraps to 0
        out[77055840u] = v34; out[77055841u] = v35; out[77055842u] = v35;
    }
}

extern "C" void kernel_launch(void* const* d_in, const int* in_sizes, int n_in,
                              void* d_out, int out_size, void* d_ws, size_t ws_size,
                              hipStream_t stream) {
    const float* probas = (const float*)d_in[0];
    float* out = (float*)d_out;
    cubify_k<<<TOTAL_BLOCKS, 256, 0, stream>>>(probas, out);
}